// Round 6
// baseline (547.609 us; speedup 1.0000x reference)
//
#include <hip/hip_runtime.h>

#define BS 16
#define CI 2048
#define NI 16
#define CO 64
#define NO 32
#define KK 2048   // CO*NO
#define GBLK 256  // blocks; each handles 8 capsules i (i = blk + il*GBLK)

__device__ __forceinline__ void load_lds16(const float* g, float* l) {
    __builtin_amdgcn_global_load_lds(
        (const __attribute__((address_space(1))) void*)g,
        (__attribute__((address_space(3))) void*)l,
        16, 0, 0);
}

#define WAITVM4 asm volatile("s_waitcnt vmcnt(4)" ::: "memory")
#define WAITVM0 asm volatile("s_waitcnt vmcnt(0)" ::: "memory")
#define WAITLGKM asm volatile("s_waitcnt lgkmcnt(0)" ::: "memory")
#define BAR __builtin_amdgcn_s_barrier

// 1024 threads: batch-half h = t>>9 (b 0-7 or 8-15), u = t&511 owns k quad 4u.
// amdgpu_waves_per_eu(4,4): pin allocator to exactly 4 waves/EU -> 128 VGPR
// budget (live set ~116). LDS limits us to 1 block/CU regardless, so extra
// occupancy the allocator could buy by spilling is worthless.
// MODE 0: iter1 (uniform route); MODE 1: iter2 (store logits); MODE 2: iter3.
template <int MODE>
__global__ __launch_bounds__(1024)
__attribute__((amdgpu_waves_per_eu(4, 4)))
void pass_kernel(
    const float* __restrict__ x,      // [BS][CI][NI]
    const float* __restrict__ w,      // [CI][NI][KK]
    const float* __restrict__ act_in, // [BS][KK]
    float* __restrict__ logits,       // [BS][CI][CO]
    float* __restrict__ partials)     // [GBLK][BS][KK]
{
    __shared__ float wbuf[2][8 * KK]; // 128 KB, double-buffered ni-half tiles
    __shared__ float xb[8][BS][NI];   // 8 KB
    __shared__ float sm[BS * 65];     // softmax exchange, padded

    const int t = threadIdx.x;        // 0..1023
    const int blk = blockIdx.x;
    const int h = t >> 9;             // batch half: 0 -> b 0-7, 1 -> b 8-15
    const int u = t & 511;
    const int k4 = 4 * u;             // this thread's k quad
    const int co = u >> 3;            // k4 / 32
    const int j8 = u & 7;             // lane within 8-group
    const int b0 = t >> 6;            // softmax cell (b0, cs)
    const int cs = t & 63;

    // ---- pre-loop staging ----
    if (t < 512) {
        int il = t >> 6, b = (t >> 2) & 15, n0 = (t & 3) * 4;
        int i = blk + il * GBLK;
        *(float4*)&xb[il][b][n0] = *(const float4*)&x[((size_t)b * CI + i) * NI + n0];
    }
    float4 a4[8];
    if constexpr (MODE != 0) {
#pragma unroll
        for (int b = 0; b < 8; ++b)
            a4[b] = *(const float4*)&act_in[(size_t)(h * 8 + b) * KK + k4];
    }
    float lg[8];
    if constexpr (MODE == 2) {
#pragma unroll
        for (int il = 0; il < 8; ++il)
            lg[il] = logits[((size_t)b0 * CI + (blk + il * GBLK)) * CO + cs];
    }
    __syncthreads();  // drains vmcnt/lgkmcnt: clean slate for counted waits

    float4 acc[8];
#pragma unroll
    for (int b = 0; b < 8; ++b) acc[b] = make_float4(0.f, 0.f, 0.f, 0.f);

    // stage one ni-half tile (8 rows = 64 KB) linearly: 4 x dwordx4 per thread.
    auto issue = [&](int hb) {
        int il = hb >> 1, p = hb & 1;
        const float* gb = w + ((size_t)(blk + il * GBLK) * NI + (size_t)p * 8) * KK + 4 * t;
        float* lb = wbuf[p] + 4 * t;
#pragma unroll
        for (int r = 0; r < 4; ++r)
            load_lds16(gb + 4096 * r, lb + 4096 * r);
    };

    auto compute_half = [&](int il, int p, float4(&dst)[8]) {
#pragma unroll
        for (int rg = 0; rg < 4; ++rg) {
            float4 wA = *(const float4*)&wbuf[p][(2 * rg) * KK + k4];
            float4 wB = *(const float4*)&wbuf[p][(2 * rg + 1) * KK + k4];
#pragma unroll
            for (int b = 0; b < 8; ++b) {
                float2 xv = *(const float2*)&xb[il][h * 8 + b][p * 8 + 2 * rg];
                dst[b].x = fmaf(xv.x, wA.x, dst[b].x);
                dst[b].y = fmaf(xv.x, wA.y, dst[b].y);
                dst[b].z = fmaf(xv.x, wA.z, dst[b].z);
                dst[b].w = fmaf(xv.x, wA.w, dst[b].w);
                dst[b].x = fmaf(xv.y, wB.x, dst[b].x);
                dst[b].y = fmaf(xv.y, wB.y, dst[b].y);
                dst[b].z = fmaf(xv.y, wB.z, dst[b].z);
                dst[b].w = fmaf(xv.y, wB.w, dst[b].w);
            }
        }
    };

    issue(0);
    issue(1);

#pragma unroll
    for (int il = 0; il < 8; ++il) {
        float4 v[8];
        if constexpr (MODE != 0) {
#pragma unroll
            for (int b = 0; b < 8; ++b) v[b] = make_float4(0.f, 0.f, 0.f, 0.f);
        }

        // ---- half 0 (ni 0..7) ----
        WAITVM4;                       // own loads of tile 2il arrived
        BAR();                         // => whole tile arrived
        if constexpr (MODE == 0) compute_half(il, 0, acc);
        else                     compute_half(il, 0, v);
        WAITLGKM;                      // my reads of buf 0 retired
        BAR();                         // everyone's reads retired
        if (il < 7) issue(2 * il + 2);

        // ---- half 1 (ni 8..15) ----
        if (il < 7) { WAITVM4; } else { WAITVM0; }
        BAR();
        if constexpr (MODE == 0) compute_half(il, 1, acc);
        else                     compute_half(il, 1, v);
        WAITLGKM;
        BAR();
        if (il < 7) issue(2 * il + 3);

        if constexpr (MODE != 0) {
            // ---- distances: per b, 8-lane reduce; static select ----
            float dpv = 0.f;
#pragma unroll
            for (int b = 0; b < 8; ++b) {
                float d = v[b].x * a4[b].x + v[b].y * a4[b].y +
                          v[b].z * a4[b].z + v[b].w * a4[b].w;
#pragma unroll
                for (int m = 1; m < 8; m <<= 1)
                    d += __shfl_xor(d, m, 8);
                if (j8 == b) dpv = d;
            }
            sm[(h * 8 + j8) * 65 + co] = dpv;
            WAITLGKM;
            BAR();

            {   // ---- softmax over co: this thread owns cell (b0, cs) ----
                float l0 = sm[b0 * 65 + cs];
                if constexpr (MODE == 1) lg[il] = l0;     // store at end
                else                     l0 += lg[il];
                float mx = l0;
#pragma unroll
                for (int m = 1; m < 64; m <<= 1)
                    mx = fmaxf(mx, __shfl_xor(mx, m, 64));
                float e = __expf(l0 - mx);
                float s = e;
#pragma unroll
                for (int m = 1; m < 64; m <<= 1)
                    s += __shfl_xor(s, m, 64);
                sm[b0 * 65 + cs] = e / s;
            }
            WAITLGKM;
            BAR();

            // ---- routed accumulate ----
#pragma unroll
            for (int b = 0; b < 8; ++b) {
                float r = sm[(h * 8 + b) * 65 + co];
                acc[b].x = fmaf(r, v[b].x, acc[b].x);
                acc[b].y = fmaf(r, v[b].y, acc[b].y);
                acc[b].z = fmaf(r, v[b].z, acc[b].z);
                acc[b].w = fmaf(r, v[b].w, acc[b].w);
            }
            WAITLGKM;
            BAR();                     // sm reads done before next il writes
        }
    }

    // ---- epilogue (vmcnt drained by il=7 half 1) ----
#pragma unroll
    for (int b = 0; b < 8; ++b)
        *(float4*)&partials[((size_t)blk * BS + h * 8 + b) * KK + k4] = acc[b];

    if constexpr (MODE == 1) {
#pragma unroll
        for (int il = 0; il < 8; ++il)
            logits[((size_t)b0 * CI + (blk + il * GBLK)) * CO + cs] = lg[il];
    }
}

// 256 blocks x 128 threads; block owns 128 outputs; 4-way split over G + LDS combine
__global__ __launch_bounds__(128) void reduce_squash(
    const float* __restrict__ partials,
    const float* __restrict__ bias,
    float* __restrict__ act_out, float scale)
{
    __shared__ float4 sred[4][32];
    const int t = threadIdx.x;
    const int blk = blockIdx.x;
    const int lane = t & 31;
    const int gp = t >> 5;
    const int o4 = blk * 128 + lane * 4;
    const int b = o4 >> 11;
    const int kk = o4 & (KK - 1);
    const float* p = partials + (size_t)b * KK + kk;
    const size_t stride = (size_t)BS * KK;

    float4 s = make_float4(0.f, 0.f, 0.f, 0.f);
#pragma unroll 4
    for (int g = gp * 64; g < gp * 64 + 64; ++g) {
        float4 v = *(const float4*)(p + (size_t)g * stride);
        s.x += v.x; s.y += v.y; s.z += v.z; s.w += v.w;
    }
    sred[gp][lane] = s;
    __syncthreads();

    if (t < 32) {
        float4 v0 = sred[0][t], v1 = sred[1][t], v2 = sred[2][t], v3 = sred[3][t];
        float4 v;
        v.x = (v0.x + v1.x) + (v2.x + v3.x);
        v.y = (v0.y + v1.y) + (v2.y + v3.y);
        v.z = (v0.z + v1.z) + (v2.z + v3.z);
        v.w = (v0.w + v1.w) + (v2.w + v3.w);
        const int ot = blk * 128 + t * 4;
        float4 bb = *(const float4*)&bias[ot & (KK - 1)];
        v.x = v.x * scale + bb.x;
        v.y = v.y * scale + bb.y;
        v.z = v.z * scale + bb.z;
        v.w = v.w * scale + bb.w;
        float n2 = v.x * v.x + v.y * v.y + v.z * v.z + v.w * v.w;
#pragma unroll
        for (int m = 1; m < 8; m <<= 1) n2 += __shfl_xor(n2, m, 8);
        float norm = sqrtf(n2);
        float sc = norm / (1.f + n2);
        float4 o = make_float4(v.x * sc, v.y * sc, v.z * sc, v.w * sc);
        *(float4*)&act_out[ot] = o;
    }
}

extern "C" void kernel_launch(void* const* d_in, const int* in_sizes, int n_in,
                              void* d_out, int out_size, void* d_ws, size_t ws_size,
                              hipStream_t stream) {
    const float* x = (const float*)d_in[0];
    const float* w = (const float*)d_in[1];
    const float* bias = (const float*)d_in[2];
    float* out = (float*)d_out;

    char* p = (char*)d_ws;
    float* partials = (float*)p; p += (size_t)GBLK * BS * KK * 4;  // 33.5 MB
    float* logits = (float*)p;   p += (size_t)BS * CI * CO * 4;    // 8 MB
    float* act1 = (float*)p;     p += (size_t)BS * KK * 4;
    float* act2 = (float*)p;

    dim3 blk(1024), grid(GBLK);
    pass_kernel<0><<<grid, blk, 0, stream>>>(x, w, nullptr, logits, partials);
    reduce_squash<<<256, 128, 0, stream>>>(partials, bias, act1, 1.0f / (float)CO);
    pass_kernel<1><<<grid, blk, 0, stream>>>(x, w, act1, logits, partials);
    reduce_squash<<<256, 128, 0, stream>>>(partials, bias, act2, 1.0f);
    pass_kernel<2><<<grid, blk, 0, stream>>>(x, w, act2, logits, partials);
    reduce_squash<<<256, 128, 0, stream>>>(partials, bias, out, 1.0f);
}

// Round 7
// 432.379 us; speedup vs baseline: 1.2665x; 1.2665x over previous
//
#include <hip/hip_runtime.h>

#define BS 16
#define CI 2048
#define NI 16
#define CO 64
#define NO 32
#define KK 2048    // CO*NO
#define PAIRS 256  // i-groups; each i is handled by 2 sibling blocks (batch halves)

__device__ __forceinline__ void load_lds16(const float* g, float* l) {
    __builtin_amdgcn_global_load_lds(
        (const __attribute__((address_space(1))) void*)g,
        (__attribute__((address_space(3))) void*)l,
        16, 0, 0);
}

#define WAITVM4 asm volatile("s_waitcnt vmcnt(4)" ::: "memory")
#define WAITVM0 asm volatile("s_waitcnt vmcnt(0)" ::: "memory")
#define WAITLGKM asm volatile("s_waitcnt lgkmcnt(0)" ::: "memory")
#define BAR __builtin_amdgcn_s_barrier

// 512 threads (empirically -> 128 VGPR), 512 blocks (2/CU).
// Sibling blocks (same pairid, half=0/1) stream identical weights -> L2 dedup;
// swizzle assumes xcd = blockIdx%8 and puts siblings on one XCD.
// Per-thread: 8 local batches x k-quad. Live set ~120 regs <= 128: no spill.
// MODE 0: iter1 (uniform route); MODE 1: iter2 (store logits); MODE 2: iter3.
template <int MODE>
__global__ __launch_bounds__(512, 2) void pass_kernel(
    const float* __restrict__ x,      // [BS][CI][NI]
    const float* __restrict__ w,      // [CI][NI][KK]
    const float* __restrict__ act_in, // [BS][KK]
    float* __restrict__ logits,       // [BS][CI][CO]
    float* __restrict__ partials)     // [PAIRS][BS][KK]
{
    __shared__ float wbuf[2][4 * KK]; // 64 KB: double-buffered quarter tiles (4 ni rows)
    __shared__ float xb[8][8][NI];    // 4 KB: x for 8 i's x this block's 8 batches
    __shared__ float sm[8 * 65];      // softmax exchange, padded

    const int t = threadIdx.x;        // 0..511
    const int phys = blockIdx.x;
    const int xcd = phys & 7;
    const int slot = phys >> 3;       // 0..63
    const int pairid = xcd * 32 + (slot >> 1);  // 0..255
    const int half = slot & 1;        // batch half: 0 -> b 0-7, 1 -> b 8-15

    const int k4 = 4 * t;             // this thread's k quad
    const int co = t >> 3;            // k4 / 32
    const int j8 = t & 7;             // lane within 8-group sharing co
    const int b0 = t >> 6;            // softmax cell local batch (0..7)
    const int cs = t & 63;            // softmax cell co

    // ---- prologue staging (before syncthreads; it drains all counters) ----
    {
        int il = t >> 6, b = (t >> 3) & 7, n0 = (t & 7) * 2;
        int i = pairid + il * PAIRS;
        float2 xv = *(const float2*)&x[((size_t)(half * 8 + b) * CI + i) * NI + n0];
        *(float2*)&xb[il][b][n0] = xv;
    }
    float4 a4[8];
    if constexpr (MODE != 0) {
#pragma unroll
        for (int b = 0; b < 8; ++b)
            a4[b] = *(const float4*)&act_in[(size_t)(half * 8 + b) * KK + k4];
    }
    float lg[8];
    if constexpr (MODE == 2) {
#pragma unroll
        for (int il = 0; il < 8; ++il)
            lg[il] = logits[((size_t)(half * 8 + b0) * CI + (pairid + il * PAIRS)) * CO + cs];
    }
    __syncthreads();  // x visible, vmcnt/lgkmcnt drained: clean slate for counted waits

    float4 acc[8];
#pragma unroll
    for (int b = 0; b < 8; ++b) acc[b] = make_float4(0.f, 0.f, 0.f, 0.f);

    // stage one quarter tile (4 ni rows = 32 KB): 4 x dwordx4 per thread, lane-linear
    auto issue = [&](int ph) {        // ph = il*4 + q, 0..31
        int il = ph >> 2, q = ph & 3;
        const float* gb = w + ((size_t)(pairid + il * PAIRS) * NI + q * 4) * KK + k4;
        float* lb = wbuf[ph & 1] + k4;
#pragma unroll
        for (int r = 0; r < 4; ++r)
            load_lds16(gb + (size_t)r * KK, lb + r * KK);
    };

    auto compute_quarter = [&](int il, int p, int q, float4(&dst)[8]) {
#pragma unroll
        for (int rg = 0; rg < 2; ++rg) {
            float4 wA = *(const float4*)&wbuf[p][(2 * rg) * KK + k4];
            float4 wB = *(const float4*)&wbuf[p][(2 * rg + 1) * KK + k4];
#pragma unroll
            for (int b = 0; b < 8; ++b) {
                float2 xv = *(const float2*)&xb[il][b][q * 4 + 2 * rg];
                dst[b].x = fmaf(xv.x, wA.x, dst[b].x);
                dst[b].y = fmaf(xv.x, wA.y, dst[b].y);
                dst[b].z = fmaf(xv.x, wA.z, dst[b].z);
                dst[b].w = fmaf(xv.x, wA.w, dst[b].w);
                dst[b].x = fmaf(xv.y, wB.x, dst[b].x);
                dst[b].y = fmaf(xv.y, wB.y, dst[b].y);
                dst[b].z = fmaf(xv.y, wB.z, dst[b].z);
                dst[b].w = fmaf(xv.y, wB.w, dst[b].w);
            }
        }
    };

    issue(0);
    issue(1);

#pragma unroll
    for (int il = 0; il < 8; ++il) {
        float4 v[8];
        if constexpr (MODE != 0) {
#pragma unroll
            for (int b = 0; b < 8; ++b) v[b] = make_float4(0.f, 0.f, 0.f, 0.f);
        }

#pragma unroll
        for (int q = 0; q < 4; ++q) {
            const int ph = il * 4 + q;
            if (ph < 31) { WAITVM4; } else { WAITVM0; }   // tile ph arrived
            BAR();                                        // for every wave
            if constexpr (MODE == 0) compute_quarter(il, ph & 1, q, acc);
            else                     compute_quarter(il, ph & 1, q, v);
            WAITLGKM;                 // my LDS reads retired
            BAR();                    // everyone's -> safe to overwrite buffer
            if (ph + 2 < 32) issue(ph + 2);
        }

        if constexpr (MODE != 0) {
            // ---- distances: per local b, 8-lane reduce; static select ----
            float dpv = 0.f;
#pragma unroll
            for (int b = 0; b < 8; ++b) {
                float d = v[b].x * a4[b].x + v[b].y * a4[b].y +
                          v[b].z * a4[b].z + v[b].w * a4[b].w;
#pragma unroll
                for (int m = 1; m < 8; m <<= 1)
                    d += __shfl_xor(d, m, 8);
                if (j8 == b) dpv = d;
            }
            sm[j8 * 65 + co] = dpv;
            WAITLGKM;
            BAR();   // raw barrier: weight prefetch stays in flight

            {   // ---- softmax over co: one wave per local batch ----
                float l0 = sm[b0 * 65 + cs];
                if constexpr (MODE == 1) lg[il] = l0;     // store at end
                else                     l0 += lg[il];
                float mx = l0;
#pragma unroll
                for (int m = 1; m < 64; m <<= 1)
                    mx = fmaxf(mx, __shfl_xor(mx, m, 64));
                float e = __expf(l0 - mx);
                float s = e;
#pragma unroll
                for (int m = 1; m < 64; m <<= 1)
                    s += __shfl_xor(s, m, 64);
                sm[b0 * 65 + cs] = e / s;
            }
            WAITLGKM;
            BAR();

            // ---- routed accumulate ----
#pragma unroll
            for (int b = 0; b < 8; ++b) {
                float r = sm[b * 65 + co];
                acc[b].x = fmaf(r, v[b].x, acc[b].x);
                acc[b].y = fmaf(r, v[b].y, acc[b].y);
                acc[b].z = fmaf(r, v[b].z, acc[b].z);
                acc[b].w = fmaf(r, v[b].w, acc[b].w);
            }
            WAITLGKM;
            BAR();   // sm reads done before next il writes
        }
    }

    // ---- epilogue (vmcnt drained by ph=31's WAITVM0) ----
#pragma unroll
    for (int b = 0; b < 8; ++b)
        *(float4*)&partials[((size_t)pairid * BS + half * 8 + b) * KK + k4] = acc[b];

    if constexpr (MODE == 1) {
#pragma unroll
        for (int il = 0; il < 8; ++il)
            logits[((size_t)(half * 8 + b0) * CI + (pairid + il * PAIRS)) * CO + cs] = lg[il];
    }
}

// 256 blocks x 128 threads; block owns 128 outputs; 4-way split over PAIRS + LDS combine
__global__ __launch_bounds__(128) void reduce_squash(
    const float* __restrict__ partials,
    const float* __restrict__ bias,
    float* __restrict__ act_out, float scale)
{
    __shared__ float4 sred[4][32];
    const int t = threadIdx.x;
    const int blk = blockIdx.x;
    const int lane = t & 31;
    const int gp = t >> 5;
    const int o4 = blk * 128 + lane * 4;
    const int b = o4 >> 11;
    const int kk = o4 & (KK - 1);
    const float* p = partials + (size_t)b * KK + kk;
    const size_t stride = (size_t)BS * KK;

    float4 s = make_float4(0.f, 0.f, 0.f, 0.f);
#pragma unroll 4
    for (int g = gp * 64; g < gp * 64 + 64; ++g) {
        float4 v = *(const float4*)(p + (size_t)g * stride);
        s.x += v.x; s.y += v.y; s.z += v.z; s.w += v.w;
    }
    sred[gp][lane] = s;
    __syncthreads();

    if (t < 32) {
        float4 v0 = sred[0][t], v1 = sred[1][t], v2 = sred[2][t], v3 = sred[3][t];
        float4 v;
        v.x = (v0.x + v1.x) + (v2.x + v3.x);
        v.y = (v0.y + v1.y) + (v2.y + v3.y);
        v.z = (v0.z + v1.z) + (v2.z + v3.z);
        v.w = (v0.w + v1.w) + (v2.w + v3.w);
        const int ot = blk * 128 + t * 4;
        float4 bb = *(const float4*)&bias[ot & (KK - 1)];
        v.x = v.x * scale + bb.x;
        v.y = v.y * scale + bb.y;
        v.z = v.z * scale + bb.z;
        v.w = v.w * scale + bb.w;
        float n2 = v.x * v.x + v.y * v.y + v.z * v.z + v.w * v.w;
#pragma unroll
        for (int m = 1; m < 8; m <<= 1) n2 += __shfl_xor(n2, m, 8);
        float norm = sqrtf(n2);
        float sc = norm / (1.f + n2);
        float4 o = make_float4(v.x * sc, v.y * sc, v.z * sc, v.w * sc);
        *(float4*)&act_out[ot] = o;
    }
}

extern "C" void kernel_launch(void* const* d_in, const int* in_sizes, int n_in,
                              void* d_out, int out_size, void* d_ws, size_t ws_size,
                              hipStream_t stream) {
    const float* x = (const float*)d_in[0];
    const float* w = (const float*)d_in[1];
    const float* bias = (const float*)d_in[2];
    float* out = (float*)d_out;

    char* p = (char*)d_ws;
    float* partials = (float*)p; p += (size_t)PAIRS * BS * KK * 4;  // 33.5 MB
    float* logits = (float*)p;   p += (size_t)BS * CI * CO * 4;     // 8 MB
    float* act1 = (float*)p;     p += (size_t)BS * KK * 4;
    float* act2 = (float*)p;

    dim3 blk(512), grid(2 * PAIRS);
    pass_kernel<0><<<grid, blk, 0, stream>>>(x, w, nullptr, logits, partials);
    reduce_squash<<<256, 128, 0, stream>>>(partials, bias, act1, 1.0f / (float)CO);
    pass_kernel<1><<<grid, blk, 0, stream>>>(x, w, act1, logits, partials);
    reduce_squash<<<256, 128, 0, stream>>>(partials, bias, act2, 1.0f);
    pass_kernel<2><<<grid, blk, 0, stream>>>(x, w, act2, logits, partials);
    reduce_squash<<<256, 128, 0, stream>>>(partials, bias, out, 1.0f);
}

// Round 8
// 419.907 us; speedup vs baseline: 1.3041x; 1.0297x over previous
//
#include <hip/hip_runtime.h>

#define BS 16
#define CI 2048
#define NI 16
#define CO 64
#define NO 32
#define KK 2048    // CO*NO
#define PAIRS 256  // i-groups; each i is handled by 2 sibling blocks (batch halves)

__device__ __forceinline__ void load_lds16(const float* g, float* l) {
    __builtin_amdgcn_global_load_lds(
        (const __attribute__((address_space(1))) void*)g,
        (__attribute__((address_space(3))) void*)l,
        16, 0, 0);
}

#define WAITVM4 asm volatile("s_waitcnt vmcnt(4)" ::: "memory")
#define WAITVM0 asm volatile("s_waitcnt vmcnt(0)" ::: "memory")
#define WAITLGKM asm volatile("s_waitcnt lgkmcnt(0)" ::: "memory")
#define BAR __builtin_amdgcn_s_barrier

// 512 threads -> 128 VGPR budget. Live set kept ~95 regs: acc[8]+v[8]+lg[8];
// act staged in LDS (actb, 64 KB) instead of registers -- this removes the
// ~24-dword/iter spill seen in r7 (WRITE 237 MB vs 42 ideal).
// Sibling blocks (same pairid, half=0/1) stream identical weights -> L2 dedup.
// MODE 0: iter1 (uniform route); MODE 1: iter2 (store logits); MODE 2: iter3.
template <int MODE>
__global__ __launch_bounds__(512, 2) void pass_kernel(
    const float* __restrict__ x,      // [BS][CI][NI]
    const float* __restrict__ w,      // [CI][NI][KK]
    const float* __restrict__ act_in, // [BS][KK]
    float* __restrict__ logits,       // [BS][CI][CO]
    float* __restrict__ partials)     // [PAIRS][BS][KK]
{
    __shared__ float wbuf[2][4 * KK]; // 64 KB: double-buffered quarter tiles (4 ni rows)
    __shared__ float actb[8][KK];     // 64 KB: act for this block's 8 batches
    __shared__ float xb[8][8][NI];    // 4 KB: x for 8 i's x this block's 8 batches
    __shared__ float sm[8 * 65];      // softmax exchange, padded

    const int t = threadIdx.x;        // 0..511
    const int phys = blockIdx.x;
    const int xcd = phys & 7;
    const int slot = phys >> 3;       // 0..63
    const int pairid = xcd * 32 + (slot >> 1);  // 0..255
    const int half = slot & 1;        // batch half: 0 -> b 0-7, 1 -> b 8-15

    const int k4 = 4 * t;             // this thread's k quad
    const int co = t >> 3;            // k4 / 32
    const int j8 = t & 7;             // lane within 8-group sharing co
    const int b0 = t >> 6;            // softmax cell local batch (0..7)
    const int cs = t & 63;            // softmax cell co

    // ---- prologue staging (before syncthreads; it drains all counters) ----
    {
        int il = t >> 6, b = (t >> 3) & 7, n0 = (t & 7) * 2;
        int i = pairid + il * PAIRS;
        float2 xv = *(const float2*)&x[((size_t)(half * 8 + b) * CI + i) * NI + n0];
        *(float2*)&xb[il][b][n0] = xv;
    }
    if constexpr (MODE != 0) {
#pragma unroll
        for (int b = 0; b < 8; ++b) {
            float4 a = *(const float4*)&act_in[(size_t)(half * 8 + b) * KK + k4];
            *(float4*)&actb[b][k4] = a;   // reg dies immediately; re-read from LDS
        }
    }
    float lg[8];
    if constexpr (MODE == 2) {
#pragma unroll
        for (int il = 0; il < 8; ++il)
            lg[il] = logits[((size_t)(half * 8 + b0) * CI + (pairid + il * PAIRS)) * CO + cs];
    }
    __syncthreads();  // x/act visible, vmcnt/lgkmcnt drained: clean slate

    float4 acc[8];
#pragma unroll
    for (int b = 0; b < 8; ++b) acc[b] = make_float4(0.f, 0.f, 0.f, 0.f);

    // stage one quarter tile (4 ni rows = 32 KB): 4 x dwordx4 per thread, lane-linear
    auto issue = [&](int ph) {        // ph = il*4 + q, 0..31
        int il = ph >> 2, q = ph & 3;
        const float* gb = w + ((size_t)(pairid + il * PAIRS) * NI + q * 4) * KK + k4;
        float* lb = wbuf[ph & 1] + k4;
#pragma unroll
        for (int r = 0; r < 4; ++r)
            load_lds16(gb + (size_t)r * KK, lb + r * KK);
    };

    auto compute_quarter = [&](int il, int p, int q, float4(&dst)[8]) {
#pragma unroll
        for (int rg = 0; rg < 2; ++rg) {
            float4 wA = *(const float4*)&wbuf[p][(2 * rg) * KK + k4];
            float4 wB = *(const float4*)&wbuf[p][(2 * rg + 1) * KK + k4];
#pragma unroll
            for (int b = 0; b < 8; ++b) {
                float2 xv = *(const float2*)&xb[il][b][q * 4 + 2 * rg];
                dst[b].x = fmaf(xv.x, wA.x, dst[b].x);
                dst[b].y = fmaf(xv.x, wA.y, dst[b].y);
                dst[b].z = fmaf(xv.x, wA.z, dst[b].z);
                dst[b].w = fmaf(xv.x, wA.w, dst[b].w);
                dst[b].x = fmaf(xv.y, wB.x, dst[b].x);
                dst[b].y = fmaf(xv.y, wB.y, dst[b].y);
                dst[b].z = fmaf(xv.y, wB.z, dst[b].z);
                dst[b].w = fmaf(xv.y, wB.w, dst[b].w);
            }
        }
    };

    issue(0);
    issue(1);

#pragma unroll
    for (int il = 0; il < 8; ++il) {
        float4 v[8];
        if constexpr (MODE != 0) {
#pragma unroll
            for (int b = 0; b < 8; ++b) v[b] = make_float4(0.f, 0.f, 0.f, 0.f);
        }

#pragma unroll
        for (int q = 0; q < 4; ++q) {
            const int ph = il * 4 + q;
            if (ph < 31) { WAITVM4; } else { WAITVM0; }   // tile ph arrived
            BAR();                                        // for every wave
            if constexpr (MODE == 0) compute_quarter(il, ph & 1, q, acc);
            else                     compute_quarter(il, ph & 1, q, v);
            WAITLGKM;                 // my LDS reads retired
            BAR();                    // everyone's -> safe to overwrite buffer
            if (ph + 2 < 32) issue(ph + 2);
        }

        if constexpr (MODE != 0) {
            // ---- distances: act from LDS (no reg pressure); 8-lane reduce ----
            float dpv = 0.f;
#pragma unroll
            for (int b = 0; b < 8; ++b) {
                float4 a = *(const float4*)&actb[b][k4];
                float d = v[b].x * a.x + v[b].y * a.y +
                          v[b].z * a.z + v[b].w * a.w;
#pragma unroll
                for (int m = 1; m < 8; m <<= 1)
                    d += __shfl_xor(d, m, 8);
                if (j8 == b) dpv = d;
            }
            sm[j8 * 65 + co] = dpv;
            WAITLGKM;
            BAR();   // raw barrier: weight prefetch stays in flight

            {   // ---- softmax over co: one wave per local batch ----
                float l0 = sm[b0 * 65 + cs];
                if constexpr (MODE == 1) lg[il] = l0;     // store at end
                else                     l0 += lg[il];
                float mx = l0;
#pragma unroll
                for (int m = 1; m < 64; m <<= 1)
                    mx = fmaxf(mx, __shfl_xor(mx, m, 64));
                float e = __expf(l0 - mx);
                float s = e;
#pragma unroll
                for (int m = 1; m < 64; m <<= 1)
                    s += __shfl_xor(s, m, 64);
                sm[b0 * 65 + cs] = e / s;
            }
            WAITLGKM;
            BAR();

            // ---- routed accumulate ----
#pragma unroll
            for (int b = 0; b < 8; ++b) {
                float r = sm[b * 65 + co];
                acc[b].x = fmaf(r, v[b].x, acc[b].x);
                acc[b].y = fmaf(r, v[b].y, acc[b].y);
                acc[b].z = fmaf(r, v[b].z, acc[b].z);
                acc[b].w = fmaf(r, v[b].w, acc[b].w);
            }
            WAITLGKM;
            BAR();   // sm reads done before next il writes
        }
    }

    // ---- epilogue (vmcnt drained by ph=31's WAITVM0) ----
#pragma unroll
    for (int b = 0; b < 8; ++b)
        *(float4*)&partials[((size_t)pairid * BS + half * 8 + b) * KK + k4] = acc[b];

    if constexpr (MODE == 1) {
#pragma unroll
        for (int il = 0; il < 8; ++il)
            logits[((size_t)(half * 8 + b0) * CI + (pairid + il * PAIRS)) * CO + cs] = lg[il];
    }
}

// 256 blocks x 128 threads; block owns 128 outputs; 4-way split over PAIRS + LDS combine
__global__ __launch_bounds__(128) void reduce_squash(
    const float* __restrict__ partials,
    const float* __restrict__ bias,
    float* __restrict__ act_out, float scale)
{
    __shared__ float4 sred[4][32];
    const int t = threadIdx.x;
    const int blk = blockIdx.x;
    const int lane = t & 31;
    const int gp = t >> 5;
    const int o4 = blk * 128 + lane * 4;
    const int b = o4 >> 11;
    const int kk = o4 & (KK - 1);
    const float* p = partials + (size_t)b * KK + kk;
    const size_t stride = (size_t)BS * KK;

    float4 s = make_float4(0.f, 0.f, 0.f, 0.f);
#pragma unroll 4
    for (int g = gp * 64; g < gp * 64 + 64; ++g) {
        float4 v = *(const float4*)(p + (size_t)g * stride);
        s.x += v.x; s.y += v.y; s.z += v.z; s.w += v.w;
    }
    sred[gp][lane] = s;
    __syncthreads();

    if (t < 32) {
        float4 v0 = sred[0][t], v1 = sred[1][t], v2 = sred[2][t], v3 = sred[3][t];
        float4 v;
        v.x = (v0.x + v1.x) + (v2.x + v3.x);
        v.y = (v0.y + v1.y) + (v2.y + v3.y);
        v.z = (v0.z + v1.z) + (v2.z + v3.z);
        v.w = (v0.w + v1.w) + (v2.w + v3.w);
        const int ot = blk * 128 + t * 4;
        float4 bb = *(const float4*)&bias[ot & (KK - 1)];
        v.x = v.x * scale + bb.x;
        v.y = v.y * scale + bb.y;
        v.z = v.z * scale + bb.z;
        v.w = v.w * scale + bb.w;
        float n2 = v.x * v.x + v.y * v.y + v.z * v.z + v.w * v.w;
#pragma unroll
        for (int m = 1; m < 8; m <<= 1) n2 += __shfl_xor(n2, m, 8);
        float norm = sqrtf(n2);
        float sc = norm / (1.f + n2);
        float4 o = make_float4(v.x * sc, v.y * sc, v.z * sc, v.w * sc);
        *(float4*)&act_out[ot] = o;
    }
}

extern "C" void kernel_launch(void* const* d_in, const int* in_sizes, int n_in,
                              void* d_out, int out_size, void* d_ws, size_t ws_size,
                              hipStream_t stream) {
    const float* x = (const float*)d_in[0];
    const float* w = (const float*)d_in[1];
    const float* bias = (const float*)d_in[2];
    float* out = (float*)d_out;

    char* p = (char*)d_ws;
    float* partials = (float*)p; p += (size_t)PAIRS * BS * KK * 4;  // 33.5 MB
    float* logits = (float*)p;   p += (size_t)BS * CI * CO * 4;     // 8 MB
    float* act1 = (float*)p;     p += (size_t)BS * KK * 4;
    float* act2 = (float*)p;

    dim3 blk(512), grid(2 * PAIRS);
    pass_kernel<0><<<grid, blk, 0, stream>>>(x, w, nullptr, logits, partials);
    reduce_squash<<<256, 128, 0, stream>>>(partials, bias, act1, 1.0f / (float)CO);
    pass_kernel<1><<<grid, blk, 0, stream>>>(x, w, act1, logits, partials);
    reduce_squash<<<256, 128, 0, stream>>>(partials, bias, act2, 1.0f);
    pass_kernel<2><<<grid, blk, 0, stream>>>(x, w, act2, logits, partials);
    reduce_squash<<<256, 128, 0, stream>>>(partials, bias, out, 1.0f);
}

// Round 9
// 251.055 us; speedup vs baseline: 2.1812x; 1.6726x over previous
//
#include <hip/hip_runtime.h>

#define BS 16
#define CI 2048
#define NI 16
#define CO 64
#define NO 32
#define KK 2048    // CO*NO
#define PAIRS 256  // i-groups; each i handled by 2 sibling blocks (batch halves)

__device__ __forceinline__ void load_lds16(const float* g, float* l) {
    __builtin_amdgcn_global_load_lds(
        (const __attribute__((address_space(1))) void*)g,
        (__attribute__((address_space(3))) void*)l,
        16, 0, 0);
}

#define WAITVM4 asm volatile("s_waitcnt vmcnt(4)" ::: "memory")
#define WAITVM0 asm volatile("s_waitcnt vmcnt(0)" ::: "memory")
#define WAITLGKM asm volatile("s_waitcnt lgkmcnt(0)" ::: "memory")
#define BAR __builtin_amdgcn_s_barrier

// 512 threads, 512 blocks (sibling pairs share weights -> L2/L3 dedup).
// KEY r9 changes vs r8:
//  * NO barriers in the weight pipeline: staging is per-thread self-sliced
//    (thread t gload_lds's wbuf[p][r][4t..4t+3] and reads back exactly those
//    slots), so own-wave vmcnt + lgkmcnt suffice. Waves free-run.
//  * il loop dynamic (#pragma unroll 1) and logits carried in LDS (lgb):
//    live set ~90 VGPR < 128 -> no spill by construction.
// MODE 0: iter1 (uniform route); MODE 1: iter2 (store logits); MODE 2: iter3.
template <int MODE>
__global__ __launch_bounds__(512, 2) void pass_kernel(
    const float* __restrict__ x,      // [BS][CI][NI]
    const float* __restrict__ w,      // [CI][NI][KK]
    const float* __restrict__ act_in, // [BS][KK]
    float* __restrict__ logits,       // [BS][CI][CO]
    float* __restrict__ partials)     // [PAIRS][BS][KK]
{
    __shared__ float wbuf[2][4 * KK]; // 64 KB: double-buffered quarter tiles
    __shared__ float actb[8][KK];     // 64 KB: act for this block's 8 batches
    __shared__ float xb[8][8][NI];    // 4 KB
    __shared__ float sm[8 * 65];      // softmax exchange, padded
    __shared__ float lgb[8][512];     // 16 KB: per-il logits (own-slot access)

    const int t = threadIdx.x;        // 0..511
    const int phys = blockIdx.x;
    const int xcd = phys & 7;
    const int slot = phys >> 3;       // 0..63
    const int pairid = xcd * 32 + (slot >> 1);  // 0..255
    const int half = slot & 1;        // batch half: 0 -> b 0-7, 1 -> b 8-15

    const int k4 = 4 * t;             // this thread's k quad
    const int co = t >> 3;            // k4 / 32
    const int j8 = t & 7;             // lane within 8-group sharing co
    const int b0 = t >> 6;            // softmax cell local batch (0..7)
    const int cs = t & 63;            // softmax cell co

    // ---- prologue staging (syncthreads below drains all counters) ----
    {
        int il = t >> 6, b = (t >> 3) & 7, n0 = (t & 7) * 2;
        int i = pairid + il * PAIRS;
        float2 xv = *(const float2*)&x[((size_t)(half * 8 + b) * CI + i) * NI + n0];
        *(float2*)&xb[il][b][n0] = xv;
    }
    if constexpr (MODE != 0) {
#pragma unroll
        for (int b = 0; b < 8; ++b) {
            float4 a = *(const float4*)&act_in[(size_t)(half * 8 + b) * KK + k4];
            *(float4*)&actb[b][k4] = a;
        }
    }
    if constexpr (MODE == 2) {
#pragma unroll 1
        for (int il = 0; il < 8; ++il)
            lgb[il][t] = logits[((size_t)(half * 8 + b0) * CI + (pairid + il * PAIRS)) * CO + cs];
    }
    __syncthreads();  // x/act/lg visible; vmcnt/lgkmcnt drained

    float4 acc[8];
#pragma unroll
    for (int b = 0; b < 8; ++b) acc[b] = make_float4(0.f, 0.f, 0.f, 0.f);

    // self-sliced quarter-tile stage: 4 x dwordx4, rows qp*4..qp*4+3, own k4.
    // buffer parity = qp&1 (tile index il*4+q has parity q&1).
    auto issue = [&](int ilp, int qp) {
        const float* gb = w + ((size_t)(pairid + ilp * PAIRS) * NI + qp * 4) * KK + k4;
        float* lb = wbuf[qp & 1] + k4;
#pragma unroll
        for (int r = 0; r < 4; ++r)
            load_lds16(gb + (size_t)r * KK, lb + r * KK);
    };

    auto compute_quarter = [&](int il, int p, int q, float4(&dst)[8]) {
#pragma unroll
        for (int rg = 0; rg < 2; ++rg) {
            float4 wA = *(const float4*)&wbuf[p][(2 * rg) * KK + k4];
            float4 wB = *(const float4*)&wbuf[p][(2 * rg + 1) * KK + k4];
#pragma unroll
            for (int b = 0; b < 8; ++b) {
                float2 xv = *(const float2*)&xb[il][b][q * 4 + 2 * rg];
                dst[b].x = fmaf(xv.x, wA.x, dst[b].x);
                dst[b].y = fmaf(xv.x, wA.y, dst[b].y);
                dst[b].z = fmaf(xv.x, wA.z, dst[b].z);
                dst[b].w = fmaf(xv.x, wA.w, dst[b].w);
                dst[b].x = fmaf(xv.y, wB.x, dst[b].x);
                dst[b].y = fmaf(xv.y, wB.y, dst[b].y);
                dst[b].z = fmaf(xv.y, wB.z, dst[b].z);
                dst[b].w = fmaf(xv.y, wB.w, dst[b].w);
            }
        }
    };

    issue(0, 0);
    issue(0, 1);

#pragma unroll 1
    for (int il = 0; il < 8; ++il) {
        float4 v[8];
        if constexpr (MODE != 0) {
#pragma unroll
            for (int b = 0; b < 8; ++b) v[b] = make_float4(0.f, 0.f, 0.f, 0.f);
        }

        // ---- 4 quarters, NO barriers: own-wave counters only ----
#pragma unroll
        for (int q = 0; q < 4; ++q) {
            if (il == 7 && q == 3) { WAITVM0; } else { WAITVM4; }
            if constexpr (MODE == 0) compute_quarter(il, q & 1, q, acc);
            else                     compute_quarter(il, q & 1, q, v);
            WAITLGKM;   // my reads of this buffer retired before I overwrite it
            if (q < 2)          issue(il, q + 2);
            else if (il < 7)    issue(il + 1, q - 2);
        }

        if constexpr (MODE != 0) {
            // ---- distances: act from LDS; 8-lane reduce; static select ----
            float dpv = 0.f;
#pragma unroll
            for (int b = 0; b < 8; ++b) {
                float4 a = *(const float4*)&actb[b][k4];
                float d = v[b].x * a.x + v[b].y * a.y +
                          v[b].z * a.z + v[b].w * a.w;
#pragma unroll
                for (int m = 1; m < 8; m <<= 1)
                    d += __shfl_xor(d, m, 8);
                if (j8 == b) dpv = d;
            }
            sm[j8 * 65 + co] = dpv;
            WAITLGKM;
            BAR();   // sm exchange (weight prefetch stays in flight)

            {   // ---- softmax over co: one wave per local batch ----
                float l0 = sm[b0 * 65 + cs];
                if constexpr (MODE == 1) lgb[il][t] = l0;   // store at end
                else                     l0 += lgb[il][t];
                float mx = l0;
#pragma unroll
                for (int m = 1; m < 64; m <<= 1)
                    mx = fmaxf(mx, __shfl_xor(mx, m, 64));
                float e = __expf(l0 - mx);
                float s = e;
#pragma unroll
                for (int m = 1; m < 64; m <<= 1)
                    s += __shfl_xor(s, m, 64);
                sm[b0 * 65 + cs] = e / s;
            }
            WAITLGKM;
            BAR();

            // ---- routed accumulate ----
#pragma unroll
            for (int b = 0; b < 8; ++b) {
                float r = sm[b * 65 + co];
                acc[b].x = fmaf(r, v[b].x, acc[b].x);
                acc[b].y = fmaf(r, v[b].y, acc[b].y);
                acc[b].z = fmaf(r, v[b].z, acc[b].z);
                acc[b].w = fmaf(r, v[b].w, acc[b].w);
            }
            WAITLGKM;
            BAR();   // sm reads done before next il's dpv writes
        }
    }

    // ---- epilogue (vmcnt drained by last quarter's WAITVM0) ----
#pragma unroll
    for (int b = 0; b < 8; ++b)
        *(float4*)&partials[((size_t)pairid * BS + half * 8 + b) * KK + k4] = acc[b];

    if constexpr (MODE == 1) {
#pragma unroll 1
        for (int il = 0; il < 8; ++il)
            logits[((size_t)(half * 8 + b0) * CI + (pairid + il * PAIRS)) * CO + cs] = lgb[il][t];
    }
}

// 256 blocks x 128 threads; block owns 128 outputs; 4-way split over PAIRS + LDS combine
__global__ __launch_bounds__(128) void reduce_squash(
    const float* __restrict__ partials,
    const float* __restrict__ bias,
    float* __restrict__ act_out, float scale)
{
    __shared__ float4 sred[4][32];
    const int t = threadIdx.x;
    const int blk = blockIdx.x;
    const int lane = t & 31;
    const int gp = t >> 5;
    const int o4 = blk * 128 + lane * 4;
    const int b = o4 >> 11;
    const int kk = o4 & (KK - 1);
    const float* p = partials + (size_t)b * KK + kk;
    const size_t stride = (size_t)BS * KK;

    float4 s = make_float4(0.f, 0.f, 0.f, 0.f);
#pragma unroll 4
    for (int g = gp * 64; g < gp * 64 + 64; ++g) {
        float4 v = *(const float4*)(p + (size_t)g * stride);
        s.x += v.x; s.y += v.y; s.z += v.z; s.w += v.w;
    }
    sred[gp][lane] = s;
    __syncthreads();

    if (t < 32) {
        float4 v0 = sred[0][t], v1 = sred[1][t], v2 = sred[2][t], v3 = sred[3][t];
        float4 v;
        v.x = (v0.x + v1.x) + (v2.x + v3.x);
        v.y = (v0.y + v1.y) + (v2.y + v3.y);
        v.z = (v0.z + v1.z) + (v2.z + v3.z);
        v.w = (v0.w + v1.w) + (v2.w + v3.w);
        const int ot = blk * 128 + t * 4;
        float4 bb = *(const float4*)&bias[ot & (KK - 1)];
        v.x = v.x * scale + bb.x;
        v.y = v.y * scale + bb.y;
        v.z = v.z * scale + bb.z;
        v.w = v.w * scale + bb.w;
        float n2 = v.x * v.x + v.y * v.y + v.z * v.z + v.w * v.w;
#pragma unroll
        for (int m = 1; m < 8; m <<= 1) n2 += __shfl_xor(n2, m, 8);
        float norm = sqrtf(n2);
        float sc = norm / (1.f + n2);
        float4 o = make_float4(v.x * sc, v.y * sc, v.z * sc, v.w * sc);
        *(float4*)&act_out[ot] = o;
    }
}

extern "C" void kernel_launch(void* const* d_in, const int* in_sizes, int n_in,
                              void* d_out, int out_size, void* d_ws, size_t ws_size,
                              hipStream_t stream) {
    const float* x = (const float*)d_in[0];
    const float* w = (const float*)d_in[1];
    const float* bias = (const float*)d_in[2];
    float* out = (float*)d_out;

    char* p = (char*)d_ws;
    float* partials = (float*)p; p += (size_t)PAIRS * BS * KK * 4;  // 33.5 MB
    float* logits = (float*)p;   p += (size_t)BS * CI * CO * 4;     // 8 MB
    float* act1 = (float*)p;     p += (size_t)BS * KK * 4;
    float* act2 = (float*)p;

    dim3 blk(512), grid(2 * PAIRS);
    pass_kernel<0><<<grid, blk, 0, stream>>>(x, w, nullptr, logits, partials);
    reduce_squash<<<256, 128, 0, stream>>>(partials, bias, act1, 1.0f / (float)CO);
    pass_kernel<1><<<grid, blk, 0, stream>>>(x, w, act1, logits, partials);
    reduce_squash<<<256, 128, 0, stream>>>(partials, bias, act2, 1.0f);
    pass_kernel<2><<<grid, blk, 0, stream>>>(x, w, act2, logits, partials);
    reduce_squash<<<256, 128, 0, stream>>>(partials, bias, out, 1.0f);
}